// Round 10
// baseline (1118.269 us; speedup 1.0000x reference)
//
#include <hip/hip_runtime.h>
#include <stdint.h>

#define T_ 512
#define B_ 32
#define V_ 512
#define L_ 128
#define NEGF (-1000000000.0f)

// Signed-i8 quantization: E = exp(trans) in ~[0.55,1.83]; SE*1.83 < 127.
#define SE_Q 69.0f
#define SU_Q 127.0f
#define LOGC 9.078313f   /* log(SE_Q * SU_Q) */

typedef int v4i __attribute__((ext_vector_type(4)));

// ---- DPP helpers -----------------------------------------------------------
template <int CTRL>
__device__ __forceinline__ int dppmov(int old_, int src) {
    return __builtin_amdgcn_update_dpp(old_, src, CTRL, 0xF, 0xF, false);
}
__device__ __forceinline__ float wave_max64(float x) {
    int xi = __float_as_int(x);
    x = fmaxf(x, __int_as_float(dppmov<0x111>(xi, xi))); xi = __float_as_int(x);
    x = fmaxf(x, __int_as_float(dppmov<0x112>(xi, xi))); xi = __float_as_int(x);
    x = fmaxf(x, __int_as_float(dppmov<0x114>(xi, xi))); xi = __float_as_int(x);
    x = fmaxf(x, __int_as_float(dppmov<0x118>(xi, xi))); xi = __float_as_int(x);
    x = fmaxf(x, __int_as_float(dppmov<0x142>(xi, xi))); xi = __float_as_int(x);
    x = fmaxf(x, __int_as_float(dppmov<0x143>(xi, xi)));
    return x;
}
// monotonic float<->uint for LDS atomicMax
__device__ __forceinline__ unsigned fkey(float f) {
    unsigned u = __float_as_uint(f);
    return (u & 0x80000000u) ? ~u : (u | 0x80000000u);
}
__device__ __forceinline__ float funkey(unsigned k) {
    unsigned u = (k & 0x80000000u) ? (k ^ 0x80000000u) : ~k;
    return __uint_as_float(u);
}

// ---------------- prep: quantize E into MFMA A-fragment layout (R9 verbatim,
// hardware-validated absmax 0.0) ---------------------------------------------
// asg_main thread tid: w=tid>>6, lane=tid&63, q=lane>>4, n=lane&15.
// Wave w owns rows 64w..64w+63 as 4 M-tiles (tt) x 8 K-tiles (kt).
// A-frag (tt,kt): lane holds A[m=64w+16tt+n][k=64kt+16q+4d+b].
__global__ void asg_prep(const float* __restrict__ trans, uint32_t* __restrict__ Et) {
    int o = blockIdx.x * blockDim.x + threadIdx.x;      // 0 .. 65535
    int d    = o & 3;
    int tid  = (o >> 2) & 511;
    int qreg = o >> 11;                                  // 0..31
    int tt = qreg >> 3, kt = qreg & 7;
    int w = tid >> 6, lane = tid & 63;
    int q = lane >> 4, n = lane & 15;
    int m  = 64 * w + 16 * tt + n;
    int k0 = 64 * kt + 16 * q + 4 * d;
    const float* tp = trans + (size_t)m * V_ + k0;
    uint32_t q0 = (uint32_t)fminf(127.0f, __expf(tp[0]) * SE_Q + 0.5f);
    uint32_t q1 = (uint32_t)fminf(127.0f, __expf(tp[1]) * SE_Q + 0.5f);
    uint32_t q2 = (uint32_t)fminf(127.0f, __expf(tp[2]) * SE_Q + 0.5f);
    uint32_t q3 = (uint32_t)fminf(127.0f, __expf(tp[3]) * SE_Q + 0.5f);
    Et[(size_t)o] = q0 | (q1 << 8) | (q2 << 16) | (q3 << 24);
}

// ---------------- fused main: blocks 0,1 = FCC(16 batches each); 2..33 = FAC -
// FCC: B-operand carries 16 batches in the 16 MFMA columns. Lane (q,n) owns
// batch n's rows {64w+16tt+4q+rg}: C elements map straight to owned alphas.
// u_lds layout: batch n's u8[512] at n*512 B, 16B-chunk c stored at chunk
// ((c+3n)&31) -> <=2-way LDS bank aliasing on both write and b128 read.
__global__ __attribute__((amdgpu_flat_work_group_size(512, 512),
                          amdgpu_waves_per_eu(2, 2)))
void asg_main(
    const float* __restrict__ lp, const uint32_t* __restrict__ Et,
    const float* __restrict__ trans, const int* __restrict__ targets,
    const int* __restrict__ ilen, const int* __restrict__ tlen,
    float* __restrict__ fcc_ws, float* __restrict__ fac_ws)
{
    __shared__ float facb[256];                       // fac double buffer
    __shared__ __align__(16) uint32_t u_lds[2048];    // 16 batches x 512 u8
    __shared__ unsigned mslot[2][16];
    __shared__ unsigned mslotE[16];
    __shared__ float    sumfv[16];
    __shared__ int      tmax_sh;

    const int bb  = blockIdx.x;
    const int tid = threadIdx.x;

    if (bb < 2) {
        // ================= FCC: 16 batches ================================
        const int bbase = bb * 16;
        const int lane  = tid & 63;
        const int w     = tid >> 6;             // wave 0..7: rows 64w..64w+63
        const int q     = lane >> 4;            // 0..3
        const int n     = lane & 15;            // batch column
        const int bg    = bbase + n;            // this lane's batch
        const int myT   = ilen[bg];
        const int myTm1 = myT - 1;

        // er: 32 uint4 A-frags (R9-validated no-spill path, shared by batches)
        uint4 er4[32];
        {
            const uint4* Eq = (const uint4*)Et;
            #pragma unroll
            for (int t8 = 0; t8 < 32; ++t8) er4[t8] = Eq[t8 * 512 + tid];
        }

        // alpha_0 = lp[0][bg][64w+16tt+4q+rg]
        float alpha[16], fin[16], lpv[16];
        #pragma unroll
        for (int tt = 0; tt < 4; ++tt) {
            float4 v = *(const float4*)(lp + (size_t)bg * V_ + 64 * w + 16 * tt + 4 * q);
            alpha[4 * tt + 0] = v.x; alpha[4 * tt + 1] = v.y;
            alpha[4 * tt + 2] = v.z; alpha[4 * tt + 3] = v.w;
        }
        #pragma unroll
        for (int j = 0; j < 16; ++j) fin[j] = alpha[j];

        if (tid < 16) {
            mslot[0][tid] = 0u; mslot[1][tid] = 0u;
            mslotE[tid] = 0u; sumfv[tid] = 0.0f;
        }
        if (tid == 0) tmax_sh = 0;
        __syncthreads();
        {
            float tmx = wave_max64((float)myT);
            if (lane == 63) atomicMax(&tmax_sh, (int)tmx);
        }
        __syncthreads();
        const int Tmax = tmax_sh;

        for (int t = 1; t < Tmax; ++t) {
            // ---- phase A: per-batch block max via 16 LDS slots
            {
                float mx = alpha[0];
                #pragma unroll
                for (int j = 1; j < 16; ++j) mx = fmaxf(mx, alpha[j]);
                atomicMax(&mslot[(t - 1) & 1][n], fkey(mx));
            }
            __syncthreads();                        // [max visible]
            const float m = funkey(mslot[(t - 1) & 1][n]);

            // ---- phase B: u8 publish (chunk-swizzled), lp load, slot reset
            #pragma unroll
            for (int tt = 0; tt < 4; ++tt) {
                uint32_t q0 = (uint32_t)(__expf(alpha[4 * tt + 0] - m) * SU_Q + 0.5f);
                uint32_t q1 = (uint32_t)(__expf(alpha[4 * tt + 1] - m) * SU_Q + 0.5f);
                uint32_t q2 = (uint32_t)(__expf(alpha[4 * tt + 2] - m) * SU_Q + 0.5f);
                uint32_t q3 = (uint32_t)(__expf(alpha[4 * tt + 3] - m) * SU_Q + 0.5f);
                uint32_t pk = q0 | (q1 << 8) | (q2 << 16) | (q3 << 24);
                u_lds[n * 128 + ((4 * w + tt + 3 * n) & 31) * 4 + q] = pk;
            }
            #pragma unroll
            for (int tt = 0; tt < 4; ++tt) {
                float4 v = *(const float4*)(lp + (size_t)t * (B_ * V_) +
                                            (size_t)bg * V_ + 64 * w + 16 * tt + 4 * q);
                lpv[4 * tt + 0] = v.x; lpv[4 * tt + 1] = v.y;
                lpv[4 * tt + 2] = v.z; lpv[4 * tt + 3] = v.w;
            }
            if (tid < 16) mslot[t & 1][tid] = 0u;
            __syncthreads();                        // [u visible]

            // ---- phase C: 8 B-frags (all 16 batches), 32 MFMA, alpha update
            v4i a0, a1, a2, a3;
            { v4i z = {0, 0, 0, 0}; a0 = z; a1 = z; a2 = z; a3 = z; }
            #pragma unroll
            for (int kt = 0; kt < 8; ++kt) {
                uint4 bf = *(const uint4*)&u_lds[(n * 32 + ((4 * kt + q + 3 * n) & 31)) * 4];
                v4i bv = __builtin_bit_cast(v4i, bf);
                a0 = __builtin_amdgcn_mfma_i32_16x16x64_i8(
                        __builtin_bit_cast(v4i, er4[0 * 8 + kt]), bv, a0, 0, 0, 0);
                a1 = __builtin_amdgcn_mfma_i32_16x16x64_i8(
                        __builtin_bit_cast(v4i, er4[1 * 8 + kt]), bv, a1, 0, 0, 0);
                a2 = __builtin_amdgcn_mfma_i32_16x16x64_i8(
                        __builtin_bit_cast(v4i, er4[2 * 8 + kt]), bv, a2, 0, 0, 0);
                a3 = __builtin_amdgcn_mfma_i32_16x16x64_i8(
                        __builtin_bit_cast(v4i, er4[3 * 8 + kt]), bv, a3, 0, 0, 0);
            }
            const float mc = m - LOGC;
            alpha[0]  = lpv[0]  + mc + __logf((float)a0.x);
            alpha[1]  = lpv[1]  + mc + __logf((float)a0.y);
            alpha[2]  = lpv[2]  + mc + __logf((float)a0.z);
            alpha[3]  = lpv[3]  + mc + __logf((float)a0.w);
            alpha[4]  = lpv[4]  + mc + __logf((float)a1.x);
            alpha[5]  = lpv[5]  + mc + __logf((float)a1.y);
            alpha[6]  = lpv[6]  + mc + __logf((float)a1.z);
            alpha[7]  = lpv[7]  + mc + __logf((float)a1.w);
            alpha[8]  = lpv[8]  + mc + __logf((float)a2.x);
            alpha[9]  = lpv[9]  + mc + __logf((float)a2.y);
            alpha[10] = lpv[10] + mc + __logf((float)a2.z);
            alpha[11] = lpv[11] + mc + __logf((float)a2.w);
            alpha[12] = lpv[12] + mc + __logf((float)a3.x);
            alpha[13] = lpv[13] + mc + __logf((float)a3.y);
            alpha[14] = lpv[14] + mc + __logf((float)a3.z);
            alpha[15] = lpv[15] + mc + __logf((float)a3.w);

            const bool lastt = (t == myTm1);
            #pragma unroll
            for (int j = 0; j < 16; ++j) fin[j] = lastt ? alpha[j] : fin[j];
        }

        // ---- epilogue: per-batch exact f32 logsumexp over fin
        {
            float mx = fin[0];
            #pragma unroll
            for (int j = 1; j < 16; ++j) mx = fmaxf(mx, fin[j]);
            atomicMax(&mslotE[n], fkey(mx));
        }
        __syncthreads();
        {
            float m2 = funkey(mslotE[n]);
            float s = 0.0f;
            #pragma unroll
            for (int j = 0; j < 16; ++j) s += __expf(fin[j] - m2);
            atomicAdd(&sumfv[n], s);
        }
        __syncthreads();
        if (tid < 16)
            fcc_ws[bbase + tid] = funkey(mslotE[tid]) + __logf(sumfv[tid]);
    } else {
        // ================= FAC (threads 0..127 active) =====================
        const int b = bb - 2;
        const int l = tid;
        const bool active = (l < L_);
        const int Tlen = ilen[b];
        const int Llen = tlen[b];

        const int tl  = active ? targets[b * L_ + l] : 0;
        const int tlm = (active && l > 0) ? targets[b * L_ + l - 1] : 0;
        const float ts = active ? trans[(size_t)tl * V_ + tl] : 0.0f;
        const float tp = (active && l > 0) ? trans[(size_t)tl * V_ + tlm] : 0.0f;

        float beta = (l == 0) ? lp[(size_t)b * V_ + tl] : NEGF;
        float em_next = active ? lp[(size_t)1 * (B_ * V_) + (size_t)b * V_ + tl] : 0.0f;

        for (int t = 1; t < Tlen; ++t) {
            float* buf = facb + (t & 1) * L_;
            if (active) buf[l] = beta;
            __syncthreads();
            float prev = (active && l > 0) ? buf[l - 1] : NEGF;
            float em = em_next;
            if (active && t + 1 < Tlen)
                em_next = lp[(size_t)(t + 1) * (B_ * V_) + (size_t)b * V_ + tl];
            if (active) {
                float st = beta + ts;
                float mv = prev + tp;
                float mx = fmaxf(st, mv);
                float mn = fminf(st, mv);
                beta = em + mx + log1pf(__expf(mn - mx));
            }
        }
        if (active && l == Llen - 1) fac_ws[b] = beta;
    }
}

// ---------------- combine ---------------------------------------------------
__global__ void asg_combine(const float* __restrict__ fcc_ws,
                            const float* __restrict__ fac_ws,
                            float* __restrict__ out) {
    int i = threadIdx.x;
    if (i < B_) out[i] = fcc_ws[i] - fac_ws[i];
}

extern "C" void kernel_launch(void* const* d_in, const int* in_sizes, int n_in,
                              void* d_out, int out_size, void* d_ws, size_t ws_size,
                              hipStream_t stream) {
    const float* lp      = (const float*)d_in[0];
    const float* trans   = (const float*)d_in[1];
    const int*   targets = (const int*)d_in[2];
    const int*   ilen    = (const int*)d_in[3];
    const int*   tlen    = (const int*)d_in[4];
    float* out = (float*)d_out;

    uint32_t* Et     = (uint32_t*)d_ws;                    // 65536 dwords = 256 KB
    float*    fcc_ws = (float*)((char*)d_ws + 65536 * 4);
    float*    fac_ws = fcc_ws + B_;

    hipLaunchKernelGGL(asg_prep, dim3(256), dim3(256), 0, stream, trans, Et);
    hipLaunchKernelGGL(asg_main, dim3(2 + B_), dim3(512), 0, stream,
                       lp, Et, trans, targets, ilen, tlen, fcc_ws, fac_ws);
    hipLaunchKernelGGL(asg_combine, dim3(1), dim3(64), 0, stream, fcc_ws, fac_ws, out);
}